// Round 3
// baseline (165.729 us; speedup 1.0000x reference)
//
#include <hip/hip_runtime.h>

#define NB 32768
#define NCH 8
#define ROWS 32  // batch rows per block -> 1024 blocks -> 4 blocks/CU

typedef __bf16 bf16x8 __attribute__((ext_vector_type(8)));
typedef float f32x4 __attribute__((ext_vector_type(4)));
typedef unsigned int u32;
typedef unsigned short u16;
typedef u32 u32x4v __attribute__((ext_vector_type(4)));
typedef u32 u32x2v __attribute__((ext_vector_type(2)));

// bf16 weights, transposed to [n][k] so MFMA B-fragments are contiguous.
// Order: 0=Wi 1=Wf 2=Wo 3=Wu 4=Ui 5=Uf 6=Uo 7=Uu
__device__ __align__(16) u16 g_wt[8 * 128 * 128];

__device__ __forceinline__ u16 f2bf(float f) {
  u32 u = __builtin_bit_cast(u32, f);
  u32 r = u + 0x7FFFu + ((u >> 16) & 1u);  // RNE
  return (u16)(r >> 16);
}

__device__ __forceinline__ float sigm(float s) {
  return __builtin_amdgcn_rcpf(1.0f + __expf(-s));
}
__device__ __forceinline__ float tanh_f(float v) {
  float e = __expf(2.0f * v);
  return 1.0f - 2.0f * __builtin_amdgcn_rcpf(e + 1.0f);
}

// Transpose + f32->bf16 all 8 weight matrices (one block per matrix).
__global__ void prep_weights(const float* __restrict__ Wi, const float* __restrict__ Wf,
                             const float* __restrict__ Wo, const float* __restrict__ Wu,
                             const float* __restrict__ Ui, const float* __restrict__ Uf,
                             const float* __restrict__ Uo, const float* __restrict__ Uu) {
  __shared__ float t[128][129];
  const float* srcs[8] = {Wi, Wf, Wo, Wu, Ui, Uf, Uo, Uu};
  const float* s = srcs[blockIdx.x];
  for (int i = threadIdx.x; i < 16384; i += 256) t[i >> 7][i & 127] = s[i];
  __syncthreads();
  u16* dst = g_wt + blockIdx.x * 16384;
  for (int i = threadIdx.x; i < 16384; i += 256) {
    int n = i >> 7, k = i & 127;
    dst[i] = f2bf(t[k][n]);  // dst[n][k] = W[k][n]
  }
}

// A-fragment from swizzled LDS tile [ROWS rows][128 k] bf16 (row stride = 16 x 16B).
// lane: row = (l&15)+16m, k = (l>>4)*8 + e ; 16B block index XOR (row&7).
__device__ __forceinline__ bf16x8 ldA(const u32x4v* buf, int row, int ks, int g) {
  u32x4v v = buf[row * 16 + ((ks * 4 + g) ^ (row & 7))];
  return __builtin_bit_cast(bf16x8, v);
}
// B-fragment from global bf16 Wt[n][k]: col = l&15, k = (l>>4)*8 + e
__device__ __forceinline__ bf16x8 ldB(const u16* wt, int col, int ks, int g) {
  return __builtin_bit_cast(bf16x8, *(const u32x4v*)(wt + col * 128 + ks * 32 + g * 8));
}

// Stage a ROWSx128 f32 tile -> bf16 swizzled LDS; optionally accumulate (h_tilde).
template <bool ACC>
__device__ __forceinline__ void stage(u32x4v* buf, const float* __restrict__ src, int tid,
                                      f32x4* htacc) {
  u32x2v* b2 = (u32x2v*)buf;
#pragma unroll
  for (int i = 0; i < ROWS / 8; ++i) {
    int q = tid + (i << 8);
    int r = q >> 5, c4 = q & 31;
    f32x4 v = *(const f32x4*)(src + r * 128 + c4 * 4);
    if (ACC) htacc[i] += v;
    u32x2v p;
    p[0] = (u32)f2bf(v[0]) | ((u32)f2bf(v[1]) << 16);
    p[1] = (u32)f2bf(v[2]) | ((u32)f2bf(v[3]) << 16);
    b2[r * 32 + (c4 ^ ((r & 7) << 1))] = p;
  }
}

// acc[2][2] += A(ROWSx128 from LDS) @ B(128x32 cols of Wt)
__device__ __forceinline__ void gemm_g(const u32x4v* a, const u16* wt, int cl, int g,
                                       int colbase, f32x4 acc[2][2]) {
#pragma unroll
  for (int ks = 0; ks < 4; ++ks) {
    bf16x8 b0 = ldB(wt, colbase + cl, ks, g);
    bf16x8 b1 = ldB(wt, colbase + 16 + cl, ks, g);
#pragma unroll
    for (int m = 0; m < 2; ++m) {
      bf16x8 av = ldA(a, m * 16 + cl, ks, g);
      acc[m][0] = __builtin_amdgcn_mfma_f32_16x16x32_bf16(av, b0, acc[m][0], 0, 0, 0);
      acc[m][1] = __builtin_amdgcn_mfma_f32_16x16x32_bf16(av, b1, acc[m][1], 0, 0, 0);
    }
  }
}

__global__ __launch_bounds__(256, 4) void tree_lstm(
    const float* __restrict__ x, const float* __restrict__ h, const float* __restrict__ C,
    const float* __restrict__ b_i, const float* __restrict__ b_f,
    const float* __restrict__ b_o, const float* __restrict__ b_u,
    float* __restrict__ out) {
  // ROWSx128 bf16 tile = ROWS*16 x 16B
  __shared__ u32x4v xs[ROWS * 16];     // x tile
  __shared__ u32x4v hb[2][ROWS * 16];  // double-buffered child h tile

  const int tid = threadIdx.x;
  const int lane = tid & 63;
  const int wv = tid >> 6;
  const int colbase = wv * 32;
  const int row0 = blockIdx.x * ROWS;
  const int g = lane >> 4;
  const int cl = lane & 15;
  const f32x4 fz = {0.f, 0.f, 0.f, 0.f};

  // U_f B-fragments resident in registers (reused for all 8 children)
  bf16x8 uf0[4], uf1[4];
  {
    const u16* Uf = g_wt + 5 * 16384;
#pragma unroll
    for (int ks = 0; ks < 4; ++ks) {
      uf0[ks] = ldB(Uf, colbase + cl, ks, g);
      uf1[ks] = ldB(Uf, colbase + 16 + cl, ks, g);
    }
  }

  f32x4 htacc[ROWS / 8];
#pragma unroll
  for (int i = 0; i < ROWS / 8; ++i) htacc[i] = fz;

  stage<false>(xs, x + (size_t)row0 * 128, tid, nullptr);
  __syncthreads();

  // stage child 0 while computing f_x = x @ W_f
  stage<true>(hb[0], h + (size_t)row0 * 128, tid, htacc);

  f32x4 afx[2][2];
#pragma unroll
  for (int m = 0; m < 2; ++m) { afx[m][0] = fz; afx[m][1] = fz; }
  gemm_g(xs, g_wt + 1 * 16384, cl, g, colbase, afx);
  __syncthreads();

  f32x4 accc[2][2];
#pragma unroll
  for (int m = 0; m < 2; ++m) { accc[m][0] = fz; accc[m][1] = fz; }
  const float bf0 = b_f[colbase + cl], bf1 = b_f[colbase + 16 + cl];

  for (int n = 0; n < NCH; ++n) {
    if (n + 1 < NCH)  // prefetch/stage next child into the other buffer
      stage<true>(hb[(n + 1) & 1], h + ((size_t)(n + 1) * NB + row0) * 128, tid, htacc);

    const u32x4v* cur = hb[n & 1];
    f32x4 f[2][2];
#pragma unroll
    for (int m = 0; m < 2; ++m) { f[m][0] = fz; f[m][1] = fz; }
#pragma unroll
    for (int ks = 0; ks < 4; ++ks)
#pragma unroll
      for (int m = 0; m < 2; ++m) {
        bf16x8 av = ldA(cur, m * 16 + cl, ks, g);
        f[m][0] = __builtin_amdgcn_mfma_f32_16x16x32_bf16(av, uf0[ks], f[m][0], 0, 0, 0);
        f[m][1] = __builtin_amdgcn_mfma_f32_16x16x32_bf16(av, uf1[ks], f[m][1], 0, 0, 0);
      }

    const float* Cn = C + ((size_t)n * NB + row0) * 128;
#pragma unroll
    for (int m = 0; m < 2; ++m)
#pragma unroll
      for (int nf = 0; nf < 2; ++nf) {
        int col = colbase + nf * 16 + cl;
        int rb = m * 16 + g * 4;
        float bfv = nf ? bf1 : bf0;
#pragma unroll
        for (int r = 0; r < 4; ++r) {
          float s = f[m][nf][r] + afx[m][nf][r] + bfv;
          accc[m][nf][r] += sigm(s) * Cn[(rb + r) * 128 + col];
        }
      }
    __syncthreads();
  }

  // h_tilde (f32 regs) -> bf16 swizzled LDS in hb[0]
  {
    u32x2v* b2 = (u32x2v*)hb[0];
#pragma unroll
    for (int i = 0; i < ROWS / 8; ++i) {
      int q = tid + (i << 8);
      int r = q >> 5, c4 = q & 31;
      u32x2v p;
      p[0] = (u32)f2bf(htacc[i][0]) | ((u32)f2bf(htacc[i][1]) << 16);
      p[1] = (u32)f2bf(htacc[i][2]) | ((u32)f2bf(htacc[i][3]) << 16);
      b2[r * 32 + (c4 ^ ((r & 7) << 1))] = p;
    }
  }
  __syncthreads();
  const u32x4v* ht = hb[0];
  float* outc = out + (size_t)NB * 128;

  // u = tanh(x@Wu + ht@Uu + bu)
  f32x4 gu[2][2];
#pragma unroll
  for (int m = 0; m < 2; ++m) { gu[m][0] = fz; gu[m][1] = fz; }
  gemm_g(xs, g_wt + 3 * 16384, cl, g, colbase, gu);
  gemm_g(ht, g_wt + 7 * 16384, cl, g, colbase, gu);
  const float bu0 = b_u[colbase + cl], bu1 = b_u[colbase + 16 + cl];
#pragma unroll
  for (int m = 0; m < 2; ++m)
#pragma unroll
    for (int nf = 0; nf < 2; ++nf)
#pragma unroll
      for (int r = 0; r < 4; ++r)
        gu[m][nf][r] = tanh_f(gu[m][nf][r] + (nf ? bu1 : bu0));

  // i gate -> c_j (write) and tanh(c) kept in accc
  f32x4 gi[2][2];
#pragma unroll
  for (int m = 0; m < 2; ++m) { gi[m][0] = fz; gi[m][1] = fz; }
  gemm_g(xs, g_wt + 0 * 16384, cl, g, colbase, gi);
  gemm_g(ht, g_wt + 4 * 16384, cl, g, colbase, gi);
  const float bi0 = b_i[colbase + cl], bi1 = b_i[colbase + 16 + cl];
#pragma unroll
  for (int m = 0; m < 2; ++m)
#pragma unroll
    for (int nf = 0; nf < 2; ++nf) {
      int col = colbase + nf * 16 + cl;
#pragma unroll
      for (int r = 0; r < 4; ++r) {
        float iv = sigm(gi[m][nf][r] + (nf ? bi1 : bi0));
        float cv = iv * gu[m][nf][r] + accc[m][nf][r];
        int row = row0 + m * 16 + g * 4 + r;
        outc[row * 128 + col] = cv;
        accc[m][nf][r] = tanh_f(cv);
      }
    }

  // o gate -> h_j
  f32x4 go[2][2];
#pragma unroll
  for (int m = 0; m < 2; ++m) { go[m][0] = fz; go[m][1] = fz; }
  gemm_g(xs, g_wt + 2 * 16384, cl, g, colbase, go);
  gemm_g(ht, g_wt + 6 * 16384, cl, g, colbase, go);
  const float bo0 = b_o[colbase + cl], bo1 = b_o[colbase + 16 + cl];
#pragma unroll
  for (int m = 0; m < 2; ++m)
#pragma unroll
    for (int nf = 0; nf < 2; ++nf) {
      int col = colbase + nf * 16 + cl;
#pragma unroll
      for (int r = 0; r < 4; ++r) {
        float ov = sigm(go[m][nf][r] + (nf ? bo1 : bo0));
        int row = row0 + m * 16 + g * 4 + r;
        out[row * 128 + col] = ov * accc[m][nf][r];
      }
    }
}

extern "C" void kernel_launch(void* const* d_in, const int* in_sizes, int n_in,
                              void* d_out, int out_size, void* d_ws, size_t ws_size,
                              hipStream_t stream) {
  (void)in_sizes; (void)n_in; (void)out_size; (void)d_ws; (void)ws_size;
  const float* x = (const float*)d_in[0];
  const float* h = (const float*)d_in[1];
  const float* C = (const float*)d_in[2];

  prep_weights<<<8, 256, 0, stream>>>(
      (const float*)d_in[3], (const float*)d_in[4], (const float*)d_in[5],
      (const float*)d_in[6], (const float*)d_in[7], (const float*)d_in[8],
      (const float*)d_in[9], (const float*)d_in[10]);

  tree_lstm<<<NB / ROWS, 256, 0, stream>>>(
      x, h, C,
      (const float*)d_in[11], (const float*)d_in[12],
      (const float*)d_in[13], (const float*)d_in[14],
      (float*)d_out);
}

// Round 4
// 140.612 us; speedup vs baseline: 1.1786x; 1.1786x over previous
//
#include <hip/hip_runtime.h>

#define NB 32768
#define NCH 8
#define ROWS 32  // rows per block -> 1024 blocks, 4 blocks/CU (LDS 40KB)

typedef __bf16 bf16x8 __attribute__((ext_vector_type(8)));
typedef float f32x4 __attribute__((ext_vector_type(4)));
typedef unsigned int u32;
typedef unsigned short u16;
typedef u32 u32x4v __attribute__((ext_vector_type(4)));
typedef u32 u32x2v __attribute__((ext_vector_type(2)));

// bf16 weights, transposed to [n][k]. Order: 0=Wi 1=Wf 2=Wo 3=Wu 4=Ui 5=Uf 6=Uo 7=Uu
__device__ __align__(16) u16 g_wt[8 * 128 * 128];

__device__ __forceinline__ u16 f2bf(float f) {
  u32 u = __builtin_bit_cast(u32, f);
  u32 r = u + 0x7FFFu + ((u >> 16) & 1u);  // RNE
  return (u16)(r >> 16);
}
__device__ __forceinline__ float sigm(float s) {
  return __builtin_amdgcn_rcpf(1.0f + __expf(-s));
}
__device__ __forceinline__ float tanh_f(float v) {
  float e = __expf(2.0f * v);
  return 1.0f - 2.0f * __builtin_amdgcn_rcpf(e + 1.0f);
}

__global__ void prep_weights(const float* __restrict__ Wi, const float* __restrict__ Wf,
                             const float* __restrict__ Wo, const float* __restrict__ Wu,
                             const float* __restrict__ Ui, const float* __restrict__ Uf,
                             const float* __restrict__ Uo, const float* __restrict__ Uu) {
  __shared__ float t[128][129];
  const float* srcs[8] = {Wi, Wf, Wo, Wu, Ui, Uf, Uo, Uu};
  const float* s = srcs[blockIdx.x];
  for (int i = threadIdx.x; i < 16384; i += 256) t[i >> 7][i & 127] = s[i];
  __syncthreads();
  u16* dst = g_wt + blockIdx.x * 16384;
  for (int i = threadIdx.x; i < 16384; i += 256) {
    int n = i >> 7, k = i & 127;
    dst[i] = f2bf(t[k][n]);
  }
}

// A-fragment from swizzled LDS tile [ROWS][128] bf16 (row = 16 x 16B units).
__device__ __forceinline__ bf16x8 ldA(const u32x4v* buf, int row, int ks, int g) {
  u32x4v v = buf[row * 16 + ((ks * 4 + g) ^ (row & 7))];
  return __builtin_bit_cast(bf16x8, v);
}
// B-fragment from global bf16 Wt[n][k]
__device__ __forceinline__ bf16x8 ldB(const u16* wt, int col, int ks, int g) {
  return __builtin_bit_cast(bf16x8, *(const u32x4v*)(wt + col * 128 + ks * 32 + g * 8));
}

// fex swizzle: dword index within [32][128] f32 exchange buffer.
// XOR bits {2,4} by (row>>2)&3 -> frag writes 2-way max, staging b128 reads conflict-free.
__device__ __forceinline__ int fxsw(int row, int dw) {
  int k = (row >> 2) & 3;
  return row * 128 + (dw ^ (((k & 1) << 4) | ((k >> 1) << 2)));
}

// staging-layout global loads: thread owns rows (tid>>5)+i*8, dwords (tid&31)*4..+3
__device__ __forceinline__ void stage_load(const float* __restrict__ src, int tid, f32x4 hv[4]) {
#pragma unroll
  for (int i = 0; i < 4; ++i) {
    int q = tid + (i << 8);
    hv[i] = *(const f32x4*)(src + (q >> 5) * 128 + (q & 31) * 4);
  }
}
template <bool ACC>
__device__ __forceinline__ void stage_write(u32x4v* buf, int tid, const f32x4 hv[4],
                                            f32x4* htacc) {
  u32x2v* b2 = (u32x2v*)buf;
#pragma unroll
  for (int i = 0; i < 4; ++i) {
    int q = tid + (i << 8);
    int r = q >> 5, c4 = q & 31;
    if (ACC) htacc[i] += hv[i];
    u32x2v p;
    p[0] = (u32)f2bf(hv[i][0]) | ((u32)f2bf(hv[i][1]) << 16);
    p[1] = (u32)f2bf(hv[i][2]) | ((u32)f2bf(hv[i][3]) << 16);
    b2[r * 32 + (c4 ^ ((r & 7) << 1))] = p;
  }
}

// acc[2][2] += A(32x128 LDS) @ B(128 x 32 cols of Wt)
__device__ __forceinline__ void gemm_g(const u32x4v* a, const u16* wt, int cl, int g,
                                       int colbase, f32x4 acc[2][2]) {
#pragma unroll
  for (int ks = 0; ks < 4; ++ks) {
    bf16x8 b0 = ldB(wt, colbase + cl, ks, g);
    bf16x8 b1 = ldB(wt, colbase + 16 + cl, ks, g);
#pragma unroll
    for (int m = 0; m < 2; ++m) {
      bf16x8 av = ldA(a, m * 16 + cl, ks, g);
      acc[m][0] = __builtin_amdgcn_mfma_f32_16x16x32_bf16(av, b0, acc[m][0], 0, 0, 0);
      acc[m][1] = __builtin_amdgcn_mfma_f32_16x16x32_bf16(av, b1, acc[m][1], 0, 0, 0);
    }
  }
}

// fragment preacts -> fex -> staging regs (barrier-protected both sides)
__device__ __forceinline__ void exch(float* fex, const f32x4 fr[2][2], int g, int cl,
                                     int colbase, int tid, f32x4 s4[4]) {
  __syncthreads();  // protect previous fex read
#pragma unroll
  for (int m = 0; m < 2; ++m)
#pragma unroll
    for (int nf = 0; nf < 2; ++nf) {
      int col = colbase + nf * 16 + cl;
#pragma unroll
      for (int r_ = 0; r_ < 4; ++r_)
        fex[fxsw(m * 16 + g * 4 + r_, col)] = fr[m][nf][r_];
    }
  __syncthreads();
  int sr = tid >> 5, sc = (tid & 31) * 4;
#pragma unroll
  for (int i = 0; i < 4; ++i)
    s4[i] = *(const f32x4*)(fex + fxsw(sr + i * 8, sc));
}

__global__ __launch_bounds__(256, 4) void tree_lstm(
    const float* __restrict__ x, const float* __restrict__ h, const float* __restrict__ C,
    const float* __restrict__ b_i, const float* __restrict__ b_f,
    const float* __restrict__ b_o, const float* __restrict__ b_u,
    float* __restrict__ out) {
  __shared__ u32x4v xs[ROWS * 16];     // 8 KB: x tile (bf16, swizzled)
  __shared__ u32x4v hb[2][ROWS * 16];  // 16 KB: child h double buffer
  __shared__ float fex[ROWS * 128];    // 16 KB: frag->staging exchange

  const int tid = threadIdx.x;
  const int lane = tid & 63;
  const int wv = tid >> 6;
  const int colbase = wv * 32;
  const int row0 = blockIdx.x * ROWS;
  const int g = lane >> 4;
  const int cl = lane & 15;
  const int sr = tid >> 5;        // staging base row
  const int sc = (tid & 31) * 4;  // staging col (dword)
  const f32x4 fz = {0.f, 0.f, 0.f, 0.f};

  // biases as staging-layout vectors
  const f32x4 bfv = *(const f32x4*)(b_f + sc);
  const f32x4 biv = *(const f32x4*)(b_i + sc);
  const f32x4 bov = *(const f32x4*)(b_o + sc);
  const f32x4 buv = *(const f32x4*)(b_u + sc);

  f32x4 htacc[4] = {fz, fz, fz, fz};

  // x tile -> LDS
  {
    f32x4 xv[4];
    stage_load(x + (size_t)row0 * 128, tid, xv);
    stage_write<false>(xs, tid, xv, nullptr);
  }
  __syncthreads();

  // child-0 h loads in flight while computing afx = x@Wf
  f32x4 hv[4];
  stage_load(h + (size_t)row0 * 128, tid, hv);

  f32x4 afx[2][2];
#pragma unroll
  for (int m = 0; m < 2; ++m) { afx[m][0] = fz; afx[m][1] = fz; }
  gemm_g(xs, g_wt + 1 * 16384, cl, g, colbase, afx);

  stage_write<true>(hb[0], tid, hv, htacc);
  __syncthreads();

  f32x4 accS[4] = {fz, fz, fz, fz};

  for (int n = 0; n < NCH; ++n) {
    // C loads first (coalesced f32x4, staging layout) so their wait
    // doesn't drain the h prefetch behind them
    const float* Cn = C + ((size_t)n * NB + row0) * 128;
    f32x4 cr[4];
#pragma unroll
    for (int i = 0; i < 4; ++i)
      cr[i] = *(const f32x4*)(Cn + (sr + i * 8) * 128 + sc);

    // h[n+1] prefetch: issue loads only (LDS write deferred past epilogue)
    if (n + 1 < NCH)
      stage_load(h + ((size_t)(n + 1) * NB + row0) * 128, tid, hv);

    // f-GEMM: h[n] @ Uf (Uf fragments refetched, L1/L2-hot)
    f32x4 f[2][2];
#pragma unroll
    for (int m = 0; m < 2; ++m) { f[m][0] = fz; f[m][1] = fz; }
    gemm_g(hb[n & 1], g_wt + 5 * 16384, cl, g, colbase, f);

    // frag->fex: s = f + afx (bias added on staging side)
#pragma unroll
    for (int m = 0; m < 2; ++m)
#pragma unroll
      for (int nf = 0; nf < 2; ++nf) {
        int col = colbase + nf * 16 + cl;
#pragma unroll
        for (int r_ = 0; r_ < 4; ++r_)
          fex[fxsw(m * 16 + g * 4 + r_, col)] = f[m][nf][r_] + afx[m][nf][r_];
      }
    __syncthreads();

    // staging epilogue: accS += sigmoid(s + b_f) * C
#pragma unroll
    for (int i = 0; i < 4; ++i) {
      f32x4 s4 = *(const f32x4*)(fex + fxsw(sr + i * 8, sc));
#pragma unroll
      for (int j = 0; j < 4; ++j)
        accS[i][j] += sigm(s4[j] + bfv[j]) * cr[i][j];
    }

    // now commit prefetched h to LDS (vmcnt hides under whole iteration)
    if (n + 1 < NCH)
      stage_write<true>(hb[(n + 1) & 1], tid, hv, htacc);
    __syncthreads();
  }

  // h_tilde (staging regs) -> bf16 swizzled LDS in hb[0]
  {
    u32x2v* b2 = (u32x2v*)hb[0];
#pragma unroll
    for (int i = 0; i < 4; ++i) {
      int q = tid + (i << 8);
      int r = q >> 5, c4 = q & 31;
      u32x2v p;
      p[0] = (u32)f2bf(htacc[i][0]) | ((u32)f2bf(htacc[i][1]) << 16);
      p[1] = (u32)f2bf(htacc[i][2]) | ((u32)f2bf(htacc[i][3]) << 16);
      b2[r * 32 + (c4 ^ ((r & 7) << 1))] = p;
    }
  }
  __syncthreads();
  const u32x4v* ht = hb[0];

  f32x4 pre[2][2], s4[4];

  // u = tanh(x@Wu + ht@Uu + bu)
#pragma unroll
  for (int m = 0; m < 2; ++m) { pre[m][0] = fz; pre[m][1] = fz; }
  gemm_g(xs, g_wt + 3 * 16384, cl, g, colbase, pre);
  gemm_g(ht, g_wt + 7 * 16384, cl, g, colbase, pre);
  exch(fex, pre, g, cl, colbase, tid, s4);
  f32x4 uS[4];
#pragma unroll
  for (int i = 0; i < 4; ++i)
#pragma unroll
    for (int j = 0; j < 4; ++j) uS[i][j] = tanh_f(s4[i][j] + buv[j]);

  // i gate -> c_j (coalesced store), keep tanh(c)
#pragma unroll
  for (int m = 0; m < 2; ++m) { pre[m][0] = fz; pre[m][1] = fz; }
  gemm_g(xs, g_wt + 0 * 16384, cl, g, colbase, pre);
  gemm_g(ht, g_wt + 4 * 16384, cl, g, colbase, pre);
  exch(fex, pre, g, cl, colbase, tid, s4);
  float* outc = out + (size_t)NB * 128;
  f32x4 tS[4];
#pragma unroll
  for (int i = 0; i < 4; ++i) {
    f32x4 cv;
#pragma unroll
    for (int j = 0; j < 4; ++j)
      cv[j] = sigm(s4[i][j] + biv[j]) * uS[i][j] + accS[i][j];
    *(f32x4*)(outc + (size_t)(row0 + sr + i * 8) * 128 + sc) = cv;
#pragma unroll
    for (int j = 0; j < 4; ++j) tS[i][j] = tanh_f(cv[j]);
  }

  // o gate -> h_j (coalesced store)
#pragma unroll
  for (int m = 0; m < 2; ++m) { pre[m][0] = fz; pre[m][1] = fz; }
  gemm_g(xs, g_wt + 2 * 16384, cl, g, colbase, pre);
  gemm_g(ht, g_wt + 6 * 16384, cl, g, colbase, pre);
  exch(fex, pre, g, cl, colbase, tid, s4);
#pragma unroll
  for (int i = 0; i < 4; ++i) {
    f32x4 hvout;
#pragma unroll
    for (int j = 0; j < 4; ++j)
      hvout[j] = sigm(s4[i][j] + bov[j]) * tS[i][j];
    *(f32x4*)(out + (size_t)(row0 + sr + i * 8) * 128 + sc) = hvout;
  }
}

extern "C" void kernel_launch(void* const* d_in, const int* in_sizes, int n_in,
                              void* d_out, int out_size, void* d_ws, size_t ws_size,
                              hipStream_t stream) {
  (void)in_sizes; (void)n_in; (void)out_size; (void)d_ws; (void)ws_size;
  const float* x = (const float*)d_in[0];
  const float* h = (const float*)d_in[1];
  const float* C = (const float*)d_in[2];

  prep_weights<<<8, 256, 0, stream>>>(
      (const float*)d_in[3], (const float*)d_in[4], (const float*)d_in[5],
      (const float*)d_in[6], (const float*)d_in[7], (const float*)d_in[8],
      (const float*)d_in[9], (const float*)d_in[10]);

  tree_lstm<<<NB / ROWS, 256, 0, stream>>>(
      x, h, C,
      (const float*)d_in[11], (const float*)d_in[12],
      (const float*)d_in[13], (const float*)d_in[14],
      (float*)d_out);
}